// Round 2
// baseline (1410.200 us; speedup 1.0000x reference)
//
#include <hip/hip_runtime.h>

typedef unsigned short u16;
typedef unsigned int   u32;
typedef unsigned long long u64;

typedef __attribute__((ext_vector_type(8)))  short short8;
typedef __attribute__((ext_vector_type(4)))  short short4v;
typedef __attribute__((ext_vector_type(4)))  float float4v;
typedef __attribute__((ext_vector_type(16))) float float16v;

#define NB 8
#define NC 512
#define NT 4096
#define NO 1536
#define SCALE_QK 0.04419417382415922f   /* 512^-0.5 */
#define LOG2E_   1.4426950408889634f

__device__ inline u16 f2b(float f){
  u32 u = __builtin_bit_cast(u32, f);
  u += 0x7fffu + ((u >> 16) & 1u);
  return (u16)(u >> 16);
}

typedef __attribute__((address_space(1))) const unsigned int as1c_uint;
typedef __attribute__((address_space(3))) unsigned int as3_uint;

__device__ inline void gload16(const void* g, void* l){
  // each lane: 16B global -> LDS at (uniform base + lane*16)
  __builtin_amdgcn_global_load_lds((as1c_uint*)g, (as3_uint*)l, 16, 0, 0);
}

__device__ inline short8 ld8pair(const u16* p){
  short4v a = *(const short4v*)(p);
  short4v b = *(const short4v*)(p + 4);
  return __builtin_shufflevector(a, b, 0,1,2,3,4,5,6,7);
}

// ---------------- k0: f32 -> bf16 weight convert ----------------
__global__ void k_cvt(const float* __restrict__ src, u16* __restrict__ dst, int n){
  int i = blockIdx.x*256 + threadIdx.x;
  if (i < n) dst[i] = f2b(src[i]);
}

// ---------------- k1: groupnorm stats (mean, rstd per (b,g)) ----------------
__global__ void k_stats(const float* __restrict__ x, float* __restrict__ stats){
  int bg = blockIdx.x;           // 256 = 8*32
  int tid = threadIdx.x;
  const float4* p = (const float4*)(x + (size_t)bg*65536);
  float s = 0.f, q = 0.f;
  for (int i=0;i<64;i++){
    float4 v = p[i*256 + tid];
    s += v.x+v.y+v.z+v.w;
    q += v.x*v.x + v.y*v.y + v.z*v.z + v.w*v.w;
  }
  __shared__ float ls[256], lq[256];
  ls[tid]=s; lq[tid]=q; __syncthreads();
  for (int off=128; off>0; off>>=1){
    if (tid < off){ ls[tid]+=ls[tid+off]; lq[tid]+=lq[tid+off]; }
    __syncthreads();
  }
  if (tid==0){
    float mean = ls[0]*(1.f/65536.f);
    float var  = lq[0]*(1.f/65536.f) - mean*mean;
    stats[bg*2]   = mean;
    stats[bg*2+1] = rsqrtf(var + 1e-5f);
  }
}

// ---------------- k2: GN apply + transpose (b,c,t)f32 -> (b,t,c)bf16 ----------------
__global__ void k_gn_apply(const float* __restrict__ x, const float* __restrict__ stats,
                           const float* __restrict__ gw, const float* __restrict__ gb,
                           u16* __restrict__ h){
  __shared__ u16 lt[64*65];
  int b = blockIdx.z, c0 = blockIdx.y*64, t0 = blockIdx.x*64;
  int tid = threadIdx.x;
  for (int it=0; it<16; it++){
    int idx = it*256 + tid;
    int cl = idx>>6, tl = idx&63;
    int c = c0 + cl;
    float v = x[((size_t)b*NC + c)*NT + t0 + tl];
    float mean = stats[(b*32 + (c>>4))*2];
    float rstd = stats[(b*32 + (c>>4))*2 + 1];
    float y = (v - mean)*rstd*gw[c] + gb[c];
    lt[cl*65 + tl] = f2b(y);
  }
  __syncthreads();
  for (int it=0; it<16; it++){
    int idx = it*256 + tid;
    int tw = idx>>6, cw = idx&63;
    h[((size_t)b*NT + t0 + tw)*NC + c0 + cw] = lt[cw*65 + tw];
  }
}

// ---------------- GEMM helpers: 128x128 tile, BK=64, 4 waves ----------------
__device__ inline void stage128(const u16* gbase, u16* lbuf, int w, int l){
  #pragma unroll
  for (int i=0;i<4;i++){
    int r0 = (w*4+i)*8;
    int lr = r0 + (l>>3);
    int gch = (l&7) ^ (lr&7);
    gload16(gbase + (size_t)lr*512 + gch*8, lbuf + r0*64);
  }
}

__device__ inline void tile_mac(const u16* sA, const u16* sB, float4v acc[4][4], int wm, int wn, int l){
  #pragma unroll
  for (int kk=0; kk<2; kk++){
    short8 af[4], bf[4];
    #pragma unroll
    for (int f=0; f<4; f++){
      int rowA = wm + f*16 + (l&15);
      int chA  = (kk*4 + (l>>4)) ^ (rowA&7);
      af[f] = *(const short8*)(sA + rowA*64 + chA*8);
      int rowB = wn + f*16 + (l&15);
      int chB  = (kk*4 + (l>>4)) ^ (rowB&7);
      bf[f] = *(const short8*)(sB + rowB*64 + chB*8);
    }
    #pragma unroll
    for (int fm=0; fm<4; fm++)
      #pragma unroll
      for (int fn=0; fn<4; fn++)
        acc[fm][fn] = __builtin_amdgcn_mfma_f32_16x16x32_bf16(af[fm], bf[fn], acc[fm][fn], 0,0,0);
  }
}

// ---------------- k3: qkv^T GEMM: D[t][o] = sum_c h[t,c] * W[o,c] + bias[o] ----------------
__global__ __launch_bounds__(256,2) void k_qkv_gemm(const u16* __restrict__ h, const u16* __restrict__ wq,
                                                    const float* __restrict__ qb, u16* __restrict__ qkv){
  __shared__ __align__(16) u16 lA[2][8192];
  __shared__ __align__(16) u16 lB[2][8192];
  int b = blockIdx.z, t0 = blockIdx.y*128, o0 = blockIdx.x*128;
  int tid = threadIdx.x, w = tid>>6, l = tid&63;
  int wm = (w&1)*64, wn = (w>>1)*64;
  float4v acc[4][4];
  #pragma unroll
  for (int i=0;i<4;i++)
    #pragma unroll
    for (int j=0;j<4;j++)
      #pragma unroll
      for (int e=0;e<4;e++) acc[i][j][e] = 0.f;
  const u16* Ab = h  + ((size_t)b*NT + t0)*NC;
  const u16* Bb = wq + (size_t)o0*NC;
  stage128(Ab, lA[0], w, l);
  stage128(Bb, lB[0], w, l);
  __syncthreads();
  for (int it=0; it<8; it++){
    int cur = it&1;
    if (it < 7){
      stage128(Ab + (it+1)*64, lA[cur^1], w, l);
      stage128(Bb + (it+1)*64, lB[cur^1], w, l);
    }
    tile_mac(lA[cur], lB[cur], acc, wm, wn, l);
    __syncthreads();
  }
  u16* ep = ((w < 2) ? (u16*)lA : (u16*)lB) + (w&1)*4352;
  #pragma unroll
  for (int fn=0; fn<4; fn++){
    float bs = qb[o0 + wn + fn*16 + (l&15)];
    #pragma unroll
    for (int fm=0; fm<4; fm++)
      #pragma unroll
      for (int r=0; r<4; r++){
        int tl_ = fm*16 + (l>>4)*4 + r;
        int ol_ = fn*16 + (l&15);
        ep[tl_*68 + ol_] = f2b(acc[fm][fn][r] + bs);
      }
  }
  __syncthreads();
  #pragma unroll
  for (int i=0;i<8;i++){
    int r  = i*8 + (l>>3);
    int c8 = (l&7)*8;
    short8 v8 = ld8pair(ep + r*68 + c8);
    *(short8*)(qkv + ((size_t)b*NT + t0 + wm + r)*NO + o0 + wn + c8) = v8;
  }
}

// ---------------- k4: v transpose: qkv(t, 1024+c) -> vct(b,c,t) ----------------
__global__ void k_vtrans(const u16* __restrict__ qkv, u16* __restrict__ vct){
  __shared__ u16 lt[64*65];
  int b = blockIdx.z, c0 = blockIdx.y*64, t0 = blockIdx.x*64;
  int tid = threadIdx.x;
  for (int it=0; it<16; it++){
    int idx = it*256 + tid;
    int tl = idx>>6, cl = idx&63;
    lt[tl*65 + cl] = qkv[((size_t)b*NT + t0+tl)*NO + 1024 + c0 + cl];
  }
  __syncthreads();
  for (int it=0; it<16; it++){
    int idx = it*256 + tid;
    int cw = idx>>6, tw = idx&63;
    vct[((size_t)b*NC + c0+cw)*NT + t0 + tw] = lt[tw*65 + cw];
  }
}

// ---------------- k5: flash attention, t-tile 128, 8 waves, double-buffered ----------------
// QK^T 16x16x32: wave w owns t-rows [w*16, w*16+16), both s-frags of the 32-s tile.
// PV 32x32x16: wave (pm=w>>1) owns t-32-block, (pc=w&1) owns 256-c half.
__global__ __launch_bounds__(512,1) void k_attn(const u16* __restrict__ qkv, const u16* __restrict__ vct,
                                                u16* __restrict__ at){
  __shared__ __align__(16) u16 lK[2][32*512];   // 2 x 32KB, row s: 64 swizzled 16B chunks
  __shared__ __align__(16) u16 lV[2][512*36];   // 2 x 36KB, row c: 32 s + 4 pad (72B stride)
  __shared__ __align__(16) u16 lP[128*36];      // row t: 32 s + 4 pad
  __shared__ __align__(16) float lAl[128];
  __shared__ __align__(16) float lLs[128];
  const int bid = blockIdx.x;
  const int b = bid & 7;                 // batch -> XCD (round-robin dispatch assumption; perf-only)
  const int t0 = (bid >> 3) * 128;
  const int tid = threadIdx.x, w = tid>>6, l = tid&63;
  const int l15 = l&15, l4 = l>>4, l31 = l&31, l5 = l>>5;
  const int pm = w>>1, pc = w&1;

  // Q fragments: wave w owns t-rows t0 + w*16 .. +16
  short8 qf[16];
  {
    const u16* qrow = qkv + ((size_t)b*NT + t0 + w*16 + l15)*NO;   // q at col 0
    #pragma unroll
    for (int ks=0; ks<16; ks++) qf[ks] = *(const short8*)(qrow + ks*32 + l4*8);
  }
  float16v acc[8];
  #pragma unroll
  for (int i=0;i<8;i++)
    #pragma unroll
    for (int j=0;j<16;j++) acc[i][j] = 0.f;
  float M_r[4] = {-1e30f,-1e30f,-1e30f,-1e30f};
  float L_r[4] = {0.f,0.f,0.f,0.f};

  u64 vreg[8];
  const u64* vrow = (const u64*)(vct + ((size_t)b*NC + tid)*NT);   // this thread's V row c=tid

  // ---- prologue: stage tile 0
  #pragma unroll
  for (int i=0;i<4;i++){
    int sl = w*4+i;
    const u16* krow = qkv + ((size_t)b*NT + sl)*NO + 512;          // k at col 512
    gload16(krow + (l ^ (sl&7))*8, &lK[0][sl*512]);
  }
  #pragma unroll
  for (int i=0;i<8;i++) vreg[i] = vrow[i];
  {
    u64* dst = (u64*)(&lV[0][tid*36]);
    #pragma unroll
    for (int i=0;i<8;i++) dst[i] = vreg[i];                        // compiler waits vmcnt for vreg
  }
  __syncthreads();

  int cur = 0;
  for (int st=0; st<128; st++){
    // ---- issue next tile's loads early (stay in flight across barrier A)
    if (st < 127){
      const int s1 = st*32 + 32;
      #pragma unroll
      for (int i=0;i<4;i++){
        int sl = w*4+i;
        const u16* krow = qkv + ((size_t)b*NT + s1 + sl)*NO + 512;
        gload16(krow + (l ^ (sl&7))*8, &lK[cur^1][sl*512]);
      }
      #pragma unroll
      for (int i=0;i<8;i++) vreg[i] = vrow[(size_t)(st+1)*8 + i];
    }

    // ---- QK^T from lK[cur]
    float4v Lf0, Lf1;
    #pragma unroll
    for (int e=0;e<4;e++){ Lf0[e]=0.f; Lf1[e]=0.f; }
    #pragma unroll
    for (int ks=0; ks<16; ks++){
      int gch = ks*4 + l4;
      int sA = l15;
      short8 b0 = *(const short8*)(&lK[cur][sA*512 + ((gch ^ (sA&7))*8)]);
      int sB = 16 + l15;
      short8 b1 = *(const short8*)(&lK[cur][sB*512 + ((gch ^ (sB&7))*8)]);
      Lf0 = __builtin_amdgcn_mfma_f32_16x16x32_bf16(qf[ks], b0, Lf0, 0,0,0);
      Lf1 = __builtin_amdgcn_mfma_f32_16x16x32_bf16(qf[ks], b1, Lf1, 0,0,0);
    }

    // ---- online softmax (t-row owned per (l4, r); reduce over 16 lanes x 2 frags)
    #pragma unroll
    for (int r=0; r<4; r++){
      float v0 = Lf0[r]*SCALE_QK, v1 = Lf1[r]*SCALE_QK;
      float mx = fmaxf(v0, v1);
      mx = fmaxf(mx, __shfl_xor(mx,1));
      mx = fmaxf(mx, __shfl_xor(mx,2));
      mx = fmaxf(mx, __shfl_xor(mx,4));
      mx = fmaxf(mx, __shfl_xor(mx,8));
      float mnew = fmaxf(M_r[r], mx);
      float al = exp2f((M_r[r] - mnew)*LOG2E_);
      float p0 = exp2f((v0 - mnew)*LOG2E_);
      float p1 = exp2f((v1 - mnew)*LOG2E_);
      float sum = p0 + p1;
      sum += __shfl_xor(sum,1); sum += __shfl_xor(sum,2);
      sum += __shfl_xor(sum,4); sum += __shfl_xor(sum,8);
      L_r[r] = L_r[r]*al + sum;
      M_r[r] = mnew;
      int tl_ = w*16 + l4*4 + r;
      lP[tl_*36 + l15]      = f2b(p0);
      lP[tl_*36 + 16 + l15] = f2b(p1);
      if (l15 == 0) lAl[tl_] = al;
    }

    // ---- barrier A: LDS-visible only; keep K/V prefetch loads in flight (no vmcnt drain)
    asm volatile("s_waitcnt lgkmcnt(0)" ::: "memory");
    __builtin_amdgcn_sched_barrier(0);
    __builtin_amdgcn_s_barrier();
    __builtin_amdgcn_sched_barrier(0);

    // ---- PV from lV[cur]: rescale acc by alpha[t], then MFMA
    {
      float4v a_[4];
      #pragma unroll
      for (int q=0;q<4;q++) a_[q] = *(const float4v*)(&lAl[pm*32 + q*8 + l5*4]);
      #pragma unroll
      for (int fn=0; fn<8; fn++)
        #pragma unroll
        for (int q=0;q<4;q++)
          #pragma unroll
          for (int rr=0;rr<4;rr++) acc[fn][q*4+rr] *= a_[q][rr];

      const u16* prow = &lP[(pm*32 + l31)*36];
      short8 pa0 = ld8pair(prow + l5*8);
      short8 pa1 = ld8pair(prow + 16 + l5*8);
      __builtin_amdgcn_s_setprio(1);
      #pragma unroll
      for (int fn=0; fn<8; fn++){
        const u16* vr_ = &lV[cur][(pc*256 + fn*32 + l31)*36];
        short8 vb0 = ld8pair(vr_ + l5*8);
        short8 vb1 = ld8pair(vr_ + 16 + l5*8);
        acc[fn] = __builtin_amdgcn_mfma_f32_32x32x16_bf16(pa0, vb0, acc[fn], 0,0,0);
        acc[fn] = __builtin_amdgcn_mfma_f32_32x32x16_bf16(pa1, vb1, acc[fn], 0,0,0);
      }
      __builtin_amdgcn_s_setprio(0);
    }

    // ---- write prefetched V regs into the other buffer (waits vmcnt for vreg only here)
    if (st < 127){
      u64* dst = (u64*)(&lV[cur^1][tid*36]);
      #pragma unroll
      for (int i=0;i<8;i++) dst[i] = vreg[i];
    }
    __syncthreads();   // full drain: K gload_lds done, all LDS ops ordered
    cur ^= 1;
  }

  // ---- epilogue: divide by row-sum, write at(b,t,c) bf16
  if (l15 == 0){
    #pragma unroll
    for (int r=0;r<4;r++) lLs[w*16 + l4*4 + r] = L_r[r];
  }
  __syncthreads();
  {
    float4v iv[4];
    #pragma unroll
    for (int q=0;q<4;q++){
      float4v t_ = *(const float4v*)(&lLs[pm*32 + q*8 + l5*4]);
      #pragma unroll
      for (int rr=0;rr<4;rr++) iv[q][rr] = 1.f/t_[rr];
    }
    #pragma unroll
    for (int fn=0; fn<8; fn++){
      int cc = pc*256 + fn*32 + l31;
      #pragma unroll
      for (int q=0;q<4;q++)
        #pragma unroll
        for (int rr=0;rr<4;rr++){
          int tt = t0 + pm*32 + rr + q*8 + l5*4;
          at[((size_t)b*NT + tt)*NC + cc] = f2b(acc[fn][q*4+rr]*iv[q][rr]);
        }
    }
  }
}

// ---------------- k6: proj GEMM + bias + residual (f32 out) ----------------
__global__ __launch_bounds__(256,2) void k_proj_res(const u16* __restrict__ wp, const u16* __restrict__ at,
                                                    const float* __restrict__ pb, const float* __restrict__ x,
                                                    float* __restrict__ out){
  __shared__ __align__(16) u16 lA[2][8192];
  __shared__ __align__(16) u16 lB[2][8192];
  int b = blockIdx.z, t0 = blockIdx.x*128, o0 = blockIdx.y*128;
  int tid = threadIdx.x, w = tid>>6, l = tid&63;
  int wm = (w&1)*64, wn = (w>>1)*64;
  float4v acc[4][4];
  #pragma unroll
  for (int i=0;i<4;i++)
    #pragma unroll
    for (int j=0;j<4;j++)
      #pragma unroll
      for (int e=0;e<4;e++) acc[i][j][e] = 0.f;
  const u16* Ab = wp + (size_t)o0*NC;
  const u16* Bb = at + ((size_t)b*NT + t0)*NC;
  stage128(Ab, lA[0], w, l);
  stage128(Bb, lB[0], w, l);
  __syncthreads();
  for (int it=0; it<8; it++){
    int cur = it&1;
    if (it < 7){
      stage128(Ab + (it+1)*64, lA[cur^1], w, l);
      stage128(Bb + (it+1)*64, lB[cur^1], w, l);
    }
    tile_mac(lA[cur], lB[cur], acc, wm, wn, l);
    __syncthreads();
  }
  #pragma unroll
  for (int fm=0; fm<4; fm++)
    #pragma unroll
    for (int r=0; r<4; r++){
      int o = o0 + wm + fm*16 + (l>>4)*4 + r;
      float bs = pb[o];
      #pragma unroll
      for (int fn=0; fn<4; fn++){
        int t = t0 + wn + fn*16 + (l&15);
        size_t idx = ((size_t)b*NC + o)*NT + t;
        out[idx] = acc[fm][fn][r] + bs + x[idx];
      }
    }
}

extern "C" void kernel_launch(void* const* d_in, const int* in_sizes, int n_in,
                              void* d_out, int out_size, void* d_ws, size_t ws_size,
                              hipStream_t stream){
  const float* x    = (const float*)d_in[0];
  const float* gnw  = (const float*)d_in[1];
  const float* gnb  = (const float*)d_in[2];
  const float* qkvw = (const float*)d_in[3];
  const float* qkvb = (const float*)d_in[4];
  const float* pw   = (const float*)d_in[5];
  const float* pb   = (const float*)d_in[6];
  float* out = (float*)d_out;

  char* ws = (char*)d_ws;
  float* stats = (float*)ws;
  u16* h   = (u16*)(ws + 4096);
  u16* qkv = (u16*)(ws + 4096 + 33554432);
  u16* vct = (u16*)(ws + 4096 + 33554432 + 100663296);
  u16* wqb = (u16*)(ws + 4096 + 33554432 + 100663296 + 33554432);
  u16* wpb = (u16*)(ws + 4096 + 33554432 + 100663296 + 33554432 + 1572864);
  u16* at  = h;

  k_cvt<<<3072, 256, 0, stream>>>(qkvw, wqb, 786432);
  k_cvt<<<1024, 256, 0, stream>>>(pw, wpb, 262144);
  k_stats<<<256, 256, 0, stream>>>(x, stats);
  k_gn_apply<<<dim3(64,8,8), 256, 0, stream>>>(x, stats, gnw, gnb, h);
  k_qkv_gemm<<<dim3(12,32,8), 256, 0, stream>>>(h, wqb, qkvb, qkv);
  k_vtrans<<<dim3(64,8,8), 256, 0, stream>>>(qkv, vct);
  k_attn<<<256, 512, 0, stream>>>(qkv, vct, at);
  k_proj_res<<<dim3(32,4,8), 256, 0, stream>>>(wpb, at, pb, x, out);
}

// Round 3
// 1078.667 us; speedup vs baseline: 1.3074x; 1.3074x over previous
//
#include <hip/hip_runtime.h>

typedef unsigned short u16;
typedef unsigned int   u32;
typedef unsigned long long u64;

typedef __attribute__((ext_vector_type(8)))  short short8;
typedef __attribute__((ext_vector_type(4)))  short short4v;
typedef __attribute__((ext_vector_type(4)))  float float4v;
typedef __attribute__((ext_vector_type(16))) float float16v;

#define NB 8
#define NC 512
#define NT 4096
#define NO 1536
#define SCALE_QK 0.04419417382415922f   /* 512^-0.5 */
#define LOG2E_   1.4426950408889634f

__device__ inline u16 f2b(float f){
  u32 u = __builtin_bit_cast(u32, f);
  u += 0x7fffu + ((u >> 16) & 1u);
  return (u16)(u >> 16);
}

typedef __attribute__((address_space(1))) const unsigned int as1c_uint;
typedef __attribute__((address_space(3))) unsigned int as3_uint;

__device__ inline void gload16(const void* g, void* l){
  // each lane: 16B global (per-lane addr) -> LDS at (wave-uniform base + lane*16)
  __builtin_amdgcn_global_load_lds((as1c_uint*)g, (as3_uint*)l, 16, 0, 0);
}

__device__ inline short8 ld8pair(const u16* p){
  short4v a = *(const short4v*)(p);
  short4v b = *(const short4v*)(p + 4);
  return __builtin_shufflevector(a, b, 0,1,2,3,4,5,6,7);
}

// ---------------- k0: f32 -> bf16 weight convert ----------------
__global__ void k_cvt(const float* __restrict__ src, u16* __restrict__ dst, int n){
  int i = blockIdx.x*256 + threadIdx.x;
  if (i < n) dst[i] = f2b(src[i]);
}

// ---------------- k1: groupnorm stats (mean, rstd per (b,g)) ----------------
__global__ void k_stats(const float* __restrict__ x, float* __restrict__ stats){
  int bg = blockIdx.x;           // 256 = 8*32
  int tid = threadIdx.x;
  const float4* p = (const float4*)(x + (size_t)bg*65536);
  float s = 0.f, q = 0.f;
  for (int i=0;i<64;i++){
    float4 v = p[i*256 + tid];
    s += v.x+v.y+v.z+v.w;
    q += v.x*v.x + v.y*v.y + v.z*v.z + v.w*v.w;
  }
  __shared__ float ls[256], lq[256];
  ls[tid]=s; lq[tid]=q; __syncthreads();
  for (int off=128; off>0; off>>=1){
    if (tid < off){ ls[tid]+=ls[tid+off]; lq[tid]+=lq[tid+off]; }
    __syncthreads();
  }
  if (tid==0){
    float mean = ls[0]*(1.f/65536.f);
    float var  = lq[0]*(1.f/65536.f) - mean*mean;
    stats[bg*2]   = mean;
    stats[bg*2+1] = rsqrtf(var + 1e-5f);
  }
}

// ---------------- k2: GN apply + transpose (b,c,t)f32 -> (b,t,c)bf16 ----------------
__global__ void k_gn_apply(const float* __restrict__ x, const float* __restrict__ stats,
                           const float* __restrict__ gw, const float* __restrict__ gb,
                           u16* __restrict__ h){
  __shared__ u16 lt[64*65];
  int b = blockIdx.z, c0 = blockIdx.y*64, t0 = blockIdx.x*64;
  int tid = threadIdx.x;
  for (int it=0; it<16; it++){
    int idx = it*256 + tid;
    int cl = idx>>6, tl = idx&63;
    int c = c0 + cl;
    float v = x[((size_t)b*NC + c)*NT + t0 + tl];
    float mean = stats[(b*32 + (c>>4))*2];
    float rstd = stats[(b*32 + (c>>4))*2 + 1];
    float y = (v - mean)*rstd*gw[c] + gb[c];
    lt[cl*65 + tl] = f2b(y);
  }
  __syncthreads();
  for (int it=0; it<16; it++){
    int idx = it*256 + tid;
    int tw = idx>>6, cw = idx&63;
    h[((size_t)b*NT + t0 + tw)*NC + c0 + cw] = lt[cw*65 + tw];
  }
}

// ---------------- GEMM helpers: 128x128 tile, BK=64, 4 waves ----------------
__device__ inline void stage128(const u16* gbase, u16* lbuf, int w, int l){
  #pragma unroll
  for (int i=0;i<4;i++){
    int r0 = (w*4+i)*8;
    int lr = r0 + (l>>3);
    int gch = (l&7) ^ (lr&7);
    gload16(gbase + (size_t)lr*512 + gch*8, lbuf + r0*64);
  }
}

__device__ inline void tile_mac(const u16* sA, const u16* sB, float4v acc[4][4], int wm, int wn, int l){
  #pragma unroll
  for (int kk=0; kk<2; kk++){
    short8 af[4], bf[4];
    #pragma unroll
    for (int f=0; f<4; f++){
      int rowA = wm + f*16 + (l&15);
      int chA  = (kk*4 + (l>>4)) ^ (rowA&7);
      af[f] = *(const short8*)(sA + rowA*64 + chA*8);
      int rowB = wn + f*16 + (l&15);
      int chB  = (kk*4 + (l>>4)) ^ (rowB&7);
      bf[f] = *(const short8*)(sB + rowB*64 + chB*8);
    }
    #pragma unroll
    for (int fm=0; fm<4; fm++)
      #pragma unroll
      for (int fn=0; fn<4; fn++)
        acc[fm][fn] = __builtin_amdgcn_mfma_f32_16x16x32_bf16(af[fm], bf[fn], acc[fm][fn], 0,0,0);
  }
}

// ---------------- k3: qkv^T GEMM: D[t][o] = sum_c h[t,c]*W[o,c] + bias[o]
//   o < 1024 (q,k): write qkv[t][o];  o >= 1024 (v): write vct[c=o-1024][t]
__global__ __launch_bounds__(256,2) void k_qkv_gemm(const u16* __restrict__ h, const u16* __restrict__ wq,
                                                    const float* __restrict__ qb, u16* __restrict__ qkv,
                                                    u16* __restrict__ vct){
  __shared__ __align__(16) u16 lA[2][8192];
  __shared__ __align__(16) u16 lB[2][8192];
  int b = blockIdx.z, t0 = blockIdx.y*128, o0 = blockIdx.x*128;
  int tid = threadIdx.x, w = tid>>6, l = tid&63;
  int wm = (w&1)*64, wn = (w>>1)*64;
  float4v acc[4][4];
  #pragma unroll
  for (int i=0;i<4;i++)
    #pragma unroll
    for (int j=0;j<4;j++)
      #pragma unroll
      for (int e=0;e<4;e++) acc[i][j][e] = 0.f;
  const u16* Ab = h  + ((size_t)b*NT + t0)*NC;
  const u16* Bb = wq + (size_t)o0*NC;
  stage128(Ab, lA[0], w, l);
  stage128(Bb, lB[0], w, l);
  __syncthreads();
  for (int it=0; it<8; it++){
    int cur = it&1;
    if (it < 7){
      stage128(Ab + (it+1)*64, lA[cur^1], w, l);
      stage128(Bb + (it+1)*64, lB[cur^1], w, l);
    }
    tile_mac(lA[cur], lB[cur], acc, wm, wn, l);
    __syncthreads();
  }
  u16* ep = ((w < 2) ? (u16*)lA : (u16*)lB) + (w&1)*4352;
  if (o0 < 1024){
    // ---- q/k epilogue: ep[t_l*68 + o_l], coalesced store to qkv
    #pragma unroll
    for (int fn=0; fn<4; fn++){
      float bs = qb[o0 + wn + fn*16 + (l&15)];
      #pragma unroll
      for (int fm=0; fm<4; fm++)
        #pragma unroll
        for (int r=0; r<4; r++){
          int tl_ = fm*16 + (l>>4)*4 + r;
          int ol_ = fn*16 + (l&15);
          ep[tl_*68 + ol_] = f2b(acc[fm][fn][r] + bs);
        }
    }
    __syncthreads();
    #pragma unroll
    for (int i=0;i<8;i++){
      int r  = i*8 + (l>>3);
      int c8 = (l&7)*8;
      short8 v8 = ld8pair(ep + r*68 + c8);
      *(short8*)(qkv + ((size_t)b*NT + t0 + wm + r)*NO + o0 + wn + c8) = v8;
    }
  } else {
    // ---- v epilogue: transposed ep[o_l*68 + t_l], store rows of vct(b,c,t)
    #pragma unroll
    for (int fn=0; fn<4; fn++){
      float bs = qb[o0 + wn + fn*16 + (l&15)];
      #pragma unroll
      for (int fm=0; fm<4; fm++)
        #pragma unroll
        for (int r=0; r<4; r++){
          int ol_ = fn*16 + (l&15);
          int tl_ = fm*16 + (l>>4)*4 + r;
          ep[ol_*68 + tl_] = f2b(acc[fm][fn][r] + bs);
        }
    }
    __syncthreads();
    u16* vrow = vct + ((size_t)b*NC + (o0-1024) + wn + l)*NT + t0 + wm;
    #pragma unroll
    for (int i=0;i<8;i++){
      short8 v8 = ld8pair(ep + l*68 + i*8);
      *(short8*)(vrow + i*8) = v8;
    }
  }
}

// ---------------- k5: flash attention, t-tile 128, 8 waves, K+V double-buffered via gload_lds ----
// QK^T 16x16x32: wave w owns t-rows [w*16,+16). PV 32x32x16: pm=w>>1 t-32-block, pc=w&1 c-half.
// lV layout: [4 s-chunks][512 c] x 16B -> PV B-frag = one b128, bank-uniform.
__global__ __launch_bounds__(512,2) void k_attn(const u16* __restrict__ qkv, const u16* __restrict__ vct,
                                                u16* __restrict__ at){
  __shared__ __align__(16) u16 lK[2][16384];   // [buf][32 s-rows][512 u16], chunk-XOR swizzled
  __shared__ __align__(16) u16 lV[2][16384];   // [buf][4 chunks][512 c][8 u16]
  __shared__ __align__(16) u16 lP[128*36];     // row t: 32 s + 4 pad
  __shared__ float lAl[128];
  __shared__ float lLs[128];
  __shared__ int   lFlag[8];
  const int bid = blockIdx.x;
  const int b = bid & 7;                 // batch == XCD (round-robin) for K/V L2 locality
  const int t0 = (bid >> 3) * 128;
  const int tid = threadIdx.x, w = tid>>6, l = tid&63;
  const int l15 = l&15, l4 = l>>4, l31 = l&31, l5 = l>>5;
  const int pm = w>>1, pc = w&1;
  const u16* qkv_b = qkv + (size_t)b*NT*NO;
  const u16* vct_b = vct + (size_t)b*NC*NT;

  // Q fragments: wave w owns t-rows t0 + w*16 .. +16
  short8 qf[16];
  {
    const u16* qrow = qkv_b + (size_t)(t0 + w*16 + l15)*NO;        // q at col 0
    #pragma unroll
    for (int ks=0; ks<16; ks++) qf[ks] = *(const short8*)(qrow + ks*32 + l4*8);
  }
  float16v acc[8];
  #pragma unroll
  for (int i=0;i<8;i++)
    #pragma unroll
    for (int j=0;j<16;j++) acc[i][j] = 0.f;
  float M_r[4] = {-1e30f,-1e30f,-1e30f,-1e30f};
  float L_r[4] = {0.f,0.f,0.f,0.f};   // per-lane partial row-sums

  // ---- prologue: stage tile 0 (K rows + V chunks), all via global_load_lds
  #pragma unroll
  for (int i=0;i<4;i++){
    int sl = w*4+i;
    gload16(qkv_b + (size_t)sl*NO + 512 + (l ^ (sl&7))*8, &lK[0][sl*512]);
  }
  #pragma unroll
  for (int i=0;i<4;i++){
    int g = w*4+i, chunk = g>>3, c0 = (g&7)*64;
    gload16(vct_b + (size_t)(c0 + l)*NT + chunk*8, &lV[0][chunk*4096 + c0*8]);
  }
  __syncthreads();

  int cur = 0;
  for (int st=0; st<128; st++){
    // ---- issue next tile's gloads (fire-and-forget; drained at end-of-iter syncthreads)
    if (st < 127){
      const int s1 = st*32 + 32;
      #pragma unroll
      for (int i=0;i<4;i++){
        int sl = w*4+i;
        gload16(qkv_b + (size_t)(s1+sl)*NO + 512 + (l ^ (sl&7))*8, &lK[cur^1][sl*512]);
      }
      #pragma unroll
      for (int i=0;i<4;i++){
        int g = w*4+i, chunk = g>>3, c0 = (g&7)*64;
        gload16(vct_b + (size_t)(c0 + l)*NT + s1 + chunk*8, &lV[cur^1][chunk*4096 + c0*8]);
      }
    }

    // ---- QK^T from lK[cur]
    float4v Lf0, Lf1;
    #pragma unroll
    for (int e=0;e<4;e++){ Lf0[e]=0.f; Lf1[e]=0.f; }
    #pragma unroll
    for (int ks=0; ks<16; ks++){
      int gch = ks*4 + l4;
      int sA = l15;
      short8 b0 = *(const short8*)(&lK[cur][sA*512 + ((gch ^ (sA&7))*8)]);
      int sB = 16 + l15;
      short8 b1 = *(const short8*)(&lK[cur][sB*512 + ((gch ^ (sB&7))*8)]);
      Lf0 = __builtin_amdgcn_mfma_f32_16x16x32_bf16(qf[ks], b0, Lf0, 0,0,0);
      Lf1 = __builtin_amdgcn_mfma_f32_16x16x32_bf16(qf[ks], b1, Lf1, 0,0,0);
    }

    // ---- online softmax: pass 1 row-max, defer-max flag; pass 2 exp + store P
    float v0[4], v1[4], mxA[4];
    bool need = false;
    #pragma unroll
    for (int r=0; r<4; r++){
      v0[r] = Lf0[r]*SCALE_QK; v1[r] = Lf1[r]*SCALE_QK;
      float mx = fmaxf(v0[r], v1[r]);
      mx = fmaxf(mx, __shfl_xor(mx,1));
      mx = fmaxf(mx, __shfl_xor(mx,2));
      mx = fmaxf(mx, __shfl_xor(mx,4));
      mx = fmaxf(mx, __shfl_xor(mx,8));
      mxA[r] = mx;
      need = need || (mx > M_r[r] + 4.0f);
    }
    int nw = __any((int)need);
    #pragma unroll
    for (int r=0; r<4; r++){
      float mnew = nw ? fmaxf(M_r[r], mxA[r]) : M_r[r];
      float al   = nw ? exp2f((M_r[r] - mnew)*LOG2E_) : 1.0f;
      float p0 = exp2f((v0[r] - mnew)*LOG2E_);
      float p1 = exp2f((v1[r] - mnew)*LOG2E_);
      L_r[r] = L_r[r]*al + (p0 + p1);
      M_r[r] = mnew;
      int tl_ = w*16 + l4*4 + r;
      lP[tl_*36 + l15]      = f2b(p0);
      lP[tl_*36 + 16 + l15] = f2b(p1);
      if (l15 == 0) lAl[tl_] = al;
    }
    if (l == 0) lFlag[w] = nw;

    // ---- barrier A: LDS-visible only; K/V prefetch gloads stay in flight (no vmcnt drain)
    asm volatile("s_waitcnt lgkmcnt(0)" ::: "memory");
    __builtin_amdgcn_sched_barrier(0);
    __builtin_amdgcn_s_barrier();
    __builtin_amdgcn_sched_barrier(0);

    // ---- PV from lV[cur]: conditional rescale, then MFMA
    {
      int doresc = lFlag[2*pm] | lFlag[2*pm+1];
      if (doresc){
        float4v a_[4];
        #pragma unroll
        for (int q=0;q<4;q++) a_[q] = *(const float4v*)(&lAl[pm*32 + q*8 + l5*4]);
        #pragma unroll
        for (int fn=0; fn<8; fn++)
          #pragma unroll
          for (int q=0;q<4;q++)
            #pragma unroll
            for (int rr=0;rr<4;rr++) acc[fn][q*4+rr] *= a_[q][rr];
      }
      const u16* prow = &lP[(pm*32 + l31)*36];
      short8 pa0 = ld8pair(prow + l5*8);
      short8 pa1 = ld8pair(prow + 16 + l5*8);
      const u16* vbase = &lV[cur][(pc*256 + l31)*8];
      __builtin_amdgcn_s_setprio(1);
      #pragma unroll
      for (int fn=0; fn<8; fn++){
        short8 vb0 = *(const short8*)(vbase + l5*4096 + fn*256);
        short8 vb1 = *(const short8*)(vbase + (2+l5)*4096 + fn*256);
        acc[fn] = __builtin_amdgcn_mfma_f32_32x32x16_bf16(pa0, vb0, acc[fn], 0,0,0);
        acc[fn] = __builtin_amdgcn_mfma_f32_32x32x16_bf16(pa1, vb1, acc[fn], 0,0,0);
      }
      __builtin_amdgcn_s_setprio(0);
    }
    __syncthreads();   // full drain: next tile's K/V gloads complete + LDS ordered
    cur ^= 1;
  }

  // ---- epilogue: reduce row-sums, divide, write at(b,t,c) bf16
  #pragma unroll
  for (int r=0; r<4; r++){
    float s = L_r[r];
    s += __shfl_xor(s,1); s += __shfl_xor(s,2);
    s += __shfl_xor(s,4); s += __shfl_xor(s,8);
    if (l15 == 0) lLs[w*16 + l4*4 + r] = s;
  }
  __syncthreads();
  {
    float4v iv[4];
    #pragma unroll
    for (int q=0;q<4;q++){
      float4v t_ = *(const float4v*)(&lLs[pm*32 + q*8 + l5*4]);
      #pragma unroll
      for (int rr=0;rr<4;rr++) iv[q][rr] = 1.f/t_[rr];
    }
    #pragma unroll
    for (int fn=0; fn<8; fn++){
      int cc = pc*256 + fn*32 + l31;
      #pragma unroll
      for (int q=0;q<4;q++)
        #pragma unroll
        for (int rr=0;rr<4;rr++){
          int tt = t0 + pm*32 + rr + q*8 + l5*4;
          at[((size_t)b*NT + tt)*NC + cc] = f2b(acc[fn][q*4+rr]*iv[q][rr]);
        }
    }
  }
}

// ---------------- k6: proj GEMM + bias + residual (f32 out) ----------------
__global__ __launch_bounds__(256,2) void k_proj_res(const u16* __restrict__ wp, const u16* __restrict__ at,
                                                    const float* __restrict__ pb, const float* __restrict__ x,
                                                    float* __restrict__ out){
  __shared__ __align__(16) u16 lA[2][8192];
  __shared__ __align__(16) u16 lB[2][8192];
  int b = blockIdx.z, t0 = blockIdx.x*128, o0 = blockIdx.y*128;
  int tid = threadIdx.x, w = tid>>6, l = tid&63;
  int wm = (w&1)*64, wn = (w>>1)*64;
  float4v acc[4][4];
  #pragma unroll
  for (int i=0;i<4;i++)
    #pragma unroll
    for (int j=0;j<4;j++)
      #pragma unroll
      for (int e=0;e<4;e++) acc[i][j][e] = 0.f;
  const u16* Ab = wp + (size_t)o0*NC;
  const u16* Bb = at + ((size_t)b*NT + t0)*NC;
  stage128(Ab, lA[0], w, l);
  stage128(Bb, lB[0], w, l);
  __syncthreads();
  for (int it=0; it<8; it++){
    int cur = it&1;
    if (it < 7){
      stage128(Ab + (it+1)*64, lA[cur^1], w, l);
      stage128(Bb + (it+1)*64, lB[cur^1], w, l);
    }
    tile_mac(lA[cur], lB[cur], acc, wm, wn, l);
    __syncthreads();
  }
  #pragma unroll
  for (int fm=0; fm<4; fm++)
    #pragma unroll
    for (int r=0; r<4; r++){
      int o = o0 + wm + fm*16 + (l>>4)*4 + r;
      float bs = pb[o];
      #pragma unroll
      for (int fn=0; fn<4; fn++){
        int t = t0 + wn + fn*16 + (l&15);
        size_t idx = ((size_t)b*NC + o)*NT + t;
        out[idx] = acc[fm][fn][r] + bs + x[idx];
      }
    }
}

extern "C" void kernel_launch(void* const* d_in, const int* in_sizes, int n_in,
                              void* d_out, int out_size, void* d_ws, size_t ws_size,
                              hipStream_t stream){
  const float* x    = (const float*)d_in[0];
  const float* gnw  = (const float*)d_in[1];
  const float* gnb  = (const float*)d_in[2];
  const float* qkvw = (const float*)d_in[3];
  const float* qkvb = (const float*)d_in[4];
  const float* pw   = (const float*)d_in[5];
  const float* pb   = (const float*)d_in[6];
  float* out = (float*)d_out;

  char* ws = (char*)d_ws;
  float* stats = (float*)ws;
  u16* h   = (u16*)(ws + 4096);
  u16* qkv = (u16*)(ws + 4096 + 33554432);
  u16* vct = (u16*)(ws + 4096 + 33554432 + 100663296);
  u16* wqb = (u16*)(ws + 4096 + 33554432 + 100663296 + 33554432);
  u16* wpb = (u16*)(ws + 4096 + 33554432 + 100663296 + 33554432 + 1572864);
  u16* at  = h;

  k_cvt<<<3072, 256, 0, stream>>>(qkvw, wqb, 786432);
  k_cvt<<<1024, 256, 0, stream>>>(pw, wpb, 262144);
  k_stats<<<256, 256, 0, stream>>>(x, stats);
  k_gn_apply<<<dim3(64,8,8), 256, 0, stream>>>(x, stats, gnw, gnb, h);
  k_qkv_gemm<<<dim3(12,32,8), 256, 0, stream>>>(h, wqb, qkvb, qkv, vct);
  k_attn<<<256, 512, 0, stream>>>(qkv, vct, at);
  k_proj_res<<<dim3(32,4,8), 256, 0, stream>>>(wpb, at, pb, x, out);
}

// Round 5
// 966.572 us; speedup vs baseline: 1.4590x; 1.1160x over previous
//
#include <hip/hip_runtime.h>

typedef unsigned short u16;
typedef unsigned int   u32;
typedef unsigned long long u64;

typedef __attribute__((ext_vector_type(8)))  short short8;
typedef __attribute__((ext_vector_type(4)))  short short4v;
typedef __attribute__((ext_vector_type(4)))  float float4v;

#define NB 8
#define NC 512
#define NT 4096
#define NO 1536
#define SCALE_QK 0.04419417382415922f   /* 512^-0.5 */
#define LOG2E_   1.4426950408889634f

__device__ inline u16 f2b(float f){
  u32 u = __builtin_bit_cast(u32, f);
  u += 0x7fffu + ((u >> 16) & 1u);
  return (u16)(u >> 16);
}

typedef __attribute__((address_space(1))) const unsigned int as1c_uint;
typedef __attribute__((address_space(3))) unsigned int as3_uint;

__device__ inline void gload16(const void* g, void* l){
  // each lane: 16B global (per-lane addr) -> LDS at (wave-uniform base + lane*16)
  __builtin_amdgcn_global_load_lds((as1c_uint*)g, (as3_uint*)l, 16, 0, 0);
}

__device__ inline short8 ld8pair(const u16* p){
  short4v a = *(const short4v*)(p);
  short4v b = *(const short4v*)(p + 4);
  return __builtin_shufflevector(a, b, 0,1,2,3,4,5,6,7);
}

// ---------------- k0: f32 -> bf16 weight convert ----------------
__global__ void k_cvt(const float* __restrict__ src, u16* __restrict__ dst, int n){
  int i = blockIdx.x*256 + threadIdx.x;
  if (i < n) dst[i] = f2b(src[i]);
}

// ---------------- k1: groupnorm stats (mean, rstd per (b,g)) ----------------
__global__ void k_stats(const float* __restrict__ x, float* __restrict__ stats){
  int bg = blockIdx.x;           // 256 = 8*32
  int tid = threadIdx.x;
  const float4* p = (const float4*)(x + (size_t)bg*65536);
  float s = 0.f, q = 0.f;
  for (int i=0;i<64;i++){
    float4 v = p[i*256 + tid];
    s += v.x+v.y+v.z+v.w;
    q += v.x*v.x + v.y*v.y + v.z*v.z + v.w*v.w;
  }
  __shared__ float ls[256], lq[256];
  ls[tid]=s; lq[tid]=q; __syncthreads();
  for (int off=128; off>0; off>>=1){
    if (tid < off){ ls[tid]+=ls[tid+off]; lq[tid]+=lq[tid+off]; }
    __syncthreads();
  }
  if (tid==0){
    float mean = ls[0]*(1.f/65536.f);
    float var  = lq[0]*(1.f/65536.f) - mean*mean;
    stats[bg*2]   = mean;
    stats[bg*2+1] = rsqrtf(var + 1e-5f);
  }
}

// ---------------- k2: GN apply + transpose (b,c,t)f32 -> (b,t,c)bf16 ----------------
__global__ void k_gn_apply(const float* __restrict__ x, const float* __restrict__ stats,
                           const float* __restrict__ gw, const float* __restrict__ gb,
                           u16* __restrict__ h){
  __shared__ u16 lt[64*65];
  int b = blockIdx.z, c0 = blockIdx.y*64, t0 = blockIdx.x*64;
  int tid = threadIdx.x;
  for (int it=0; it<16; it++){
    int idx = it*256 + tid;
    int cl = idx>>6, tl = idx&63;
    int c = c0 + cl;
    float v = x[((size_t)b*NC + c)*NT + t0 + tl];
    float mean = stats[(b*32 + (c>>4))*2];
    float rstd = stats[(b*32 + (c>>4))*2 + 1];
    float y = (v - mean)*rstd*gw[c] + gb[c];
    lt[cl*65 + tl] = f2b(y);
  }
  __syncthreads();
  for (int it=0; it<16; it++){
    int idx = it*256 + tid;
    int tw = idx>>6, cw = idx&63;
    h[((size_t)b*NT + t0 + tw)*NC + c0 + cw] = lt[cw*65 + tw];
  }
}

// ---------------- GEMM helpers: 128x128 tile, BK=64, 4 waves ----------------
__device__ inline void stage128(const u16* gbase, u16* lbuf, int w, int l){
  #pragma unroll
  for (int i=0;i<4;i++){
    int r0 = (w*4+i)*8;
    int lr = r0 + (l>>3);
    int gch = (l&7) ^ (lr&7);
    gload16(gbase + (size_t)lr*512 + gch*8, lbuf + r0*64);
  }
}

__device__ inline void tile_mac(const u16* sA, const u16* sB, float4v acc[4][4], int wm, int wn, int l){
  #pragma unroll
  for (int kk=0; kk<2; kk++){
    short8 af[4], bf[4];
    #pragma unroll
    for (int f=0; f<4; f++){
      int rowA = wm + f*16 + (l&15);
      int chA  = (kk*4 + (l>>4)) ^ (rowA&7);
      af[f] = *(const short8*)(sA + rowA*64 + chA*8);
      int rowB = wn + f*16 + (l&15);
      int chB  = (kk*4 + (l>>4)) ^ (rowB&7);
      bf[f] = *(const short8*)(sB + rowB*64 + chB*8);
    }
    #pragma unroll
    for (int fm=0; fm<4; fm++)
      #pragma unroll
      for (int fn=0; fn<4; fn++)
        acc[fm][fn] = __builtin_amdgcn_mfma_f32_16x16x32_bf16(af[fm], bf[fn], acc[fm][fn], 0,0,0);
  }
}

// ---------------- k3: qkv^T GEMM: D[t][o] = sum_c h[t,c]*W[o,c] + bias[o]
//   o < 1024 (q,k): write qkv[t][o];  o >= 1024 (v): write vct[c=o-1024][t]
__global__ __launch_bounds__(256,2) void k_qkv_gemm(const u16* __restrict__ h, const u16* __restrict__ wq,
                                                    const float* __restrict__ qb, u16* __restrict__ qkv,
                                                    u16* __restrict__ vct){
  __shared__ __align__(16) u16 lA[2][8192];
  __shared__ __align__(16) u16 lB[2][8192];
  int b = blockIdx.z, t0 = blockIdx.y*128, o0 = blockIdx.x*128;
  int tid = threadIdx.x, w = tid>>6, l = tid&63;
  int wm = (w&1)*64, wn = (w>>1)*64;
  float4v acc[4][4];
  #pragma unroll
  for (int i=0;i<4;i++)
    #pragma unroll
    for (int j=0;j<4;j++)
      #pragma unroll
      for (int e=0;e<4;e++) acc[i][j][e] = 0.f;
  const u16* Ab = h  + ((size_t)b*NT + t0)*NC;
  const u16* Bb = wq + (size_t)o0*NC;
  stage128(Ab, lA[0], w, l);
  stage128(Bb, lB[0], w, l);
  __syncthreads();
  for (int it=0; it<8; it++){
    int cur = it&1;
    if (it < 7){
      stage128(Ab + (it+1)*64, lA[cur^1], w, l);
      stage128(Bb + (it+1)*64, lB[cur^1], w, l);
    }
    tile_mac(lA[cur], lB[cur], acc, wm, wn, l);
    __syncthreads();
  }
  u16* ep = ((w < 2) ? (u16*)lA : (u16*)lB) + (w&1)*4352;
  if (o0 < 1024){
    #pragma unroll
    for (int fn=0; fn<4; fn++){
      float bs = qb[o0 + wn + fn*16 + (l&15)];
      #pragma unroll
      for (int fm=0; fm<4; fm++)
        #pragma unroll
        for (int r=0; r<4; r++){
          int tl_ = fm*16 + (l>>4)*4 + r;
          int ol_ = fn*16 + (l&15);
          ep[tl_*68 + ol_] = f2b(acc[fm][fn][r] + bs);
        }
    }
    __syncthreads();
    #pragma unroll
    for (int i=0;i<8;i++){
      int r  = i*8 + (l>>3);
      int c8 = (l&7)*8;
      short8 v8 = ld8pair(ep + r*68 + c8);
      *(short8*)(qkv + ((size_t)b*NT + t0 + wm + r)*NO + o0 + wn + c8) = v8;
    }
  } else {
    #pragma unroll
    for (int fn=0; fn<4; fn++){
      float bs = qb[o0 + wn + fn*16 + (l&15)];
      #pragma unroll
      for (int fm=0; fm<4; fm++)
        #pragma unroll
        for (int r=0; r<4; r++){
          int ol_ = fn*16 + (l&15);
          int tl_ = fm*16 + (l>>4)*4 + r;
          ep[ol_*68 + tl_] = f2b(acc[fm][fn][r] + bs);
        }
    }
    __syncthreads();
    u16* vrow = vct + ((size_t)b*NC + (o0-1024) + wn + l)*NT + t0 + wm;
    #pragma unroll
    for (int i=0;i<8;i++){
      short8 v8 = ld8pair(ep + l*68 + i*8);
      *(short8*)(vrow + i*8) = v8;
    }
  }
}

// ---------------- k5: flash attention, barrier-free per-wave dataflow ----------------
// Wave w is self-contained for t-rows [w*16, w*16+16): QK^T -> in-lane softmax ->
// own P region -> PV over all 512 c. Only one __syncthreads per s-tile (buffer swap).
// QK^T 16x16x32: lane holds S[t=l4*4+r][s=l15 / 16+l15]  (same t-ownership as PV acc).
// PV 16x16x32, k=32 = full s-tile: A = P[16t x 32s] (one b128 re-read), B from lV chunks.
__global__ __launch_bounds__(512,2) void k_attn(const u16* __restrict__ qkv, const u16* __restrict__ vct,
                                                u16* __restrict__ at){
  __shared__ __align__(16) u16 lK[2][16384];   // [buf][32 s-rows][512 u16], chunk-XOR swizzled
  __shared__ __align__(16) u16 lV[2][16384];   // [buf][4 s-chunks][512 c][8 u16]
  __shared__ __align__(16) u16 lP[8*16*40];    // per-wave: 16 t-rows x (32 s + 8 pad)
  const int bid = blockIdx.x;
  const int b = bid & 7;                 // batch == XCD (round-robin) for K/V L2 locality
  const int t0 = (bid >> 3) * 128;
  const int tid = threadIdx.x, w = tid>>6, l = tid&63;
  const int l15 = l&15, l4 = l>>4;
  const u16* qkv_b = qkv + (size_t)b*NT*NO;
  const u16* vct_b = vct + (size_t)b*NC*NT;
  u16* lPw = lP + w*640;                 // this wave's P region (pitch 40 u16)

  // Q fragments: wave w owns t-rows t0 + w*16 .. +16
  short8 qf[16];
  {
    const u16* qrow = qkv_b + (size_t)(t0 + w*16 + l15)*NO;        // q at col 0
    #pragma unroll
    for (int ks=0; ks<16; ks++) qf[ks] = *(const short8*)(qrow + ks*32 + l4*8);
  }
  float4v acc[32];                       // D[t=l4*4+r][c = ct*16 + l15], ct=0..31
  #pragma unroll
  for (int i=0;i<32;i++)
    #pragma unroll
    for (int e=0;e<4;e++) acc[i][e] = 0.f;
  float M_r[4] = {-1e30f,-1e30f,-1e30f,-1e30f};
  float L_r[4] = {0.f,0.f,0.f,0.f};      // per-lane partial row-sums (s = l15, 16+l15)

  // ---- prologue: stage tile 0 (K rows + V chunks) via global_load_lds
  #pragma unroll
  for (int i=0;i<4;i++){
    int sl = w*4+i;
    gload16(qkv_b + (size_t)sl*NO + 512 + (l ^ (sl&7))*8, &lK[0][sl*512]);
  }
  #pragma unroll
  for (int i=0;i<4;i++){
    int g = w*4+i, chunk = g>>3, c0 = (g&7)*64;
    gload16(vct_b + (size_t)(c0 + l)*NT + chunk*8, &lV[0][chunk*4096 + c0*8]);
  }
  __syncthreads();

  int cur = 0;
  for (int st=0; st<128; st++){
    // ---- issue next tile's gloads (fire-and-forget; drained at end-of-iter syncthreads)
    if (st < 127){
      const int s1 = st*32 + 32;
      #pragma unroll
      for (int i=0;i<4;i++){
        int sl = w*4+i;
        gload16(qkv_b + (size_t)(s1+sl)*NO + 512 + (l ^ (sl&7))*8, &lK[cur^1][sl*512]);
      }
      #pragma unroll
      for (int i=0;i<4;i++){
        int g = w*4+i, chunk = g>>3, c0 = (g&7)*64;
        gload16(vct_b + (size_t)(c0 + l)*NT + s1 + chunk*8, &lV[cur^1][chunk*4096 + c0*8]);
      }
    }

    // ---- QK^T from lK[cur]
    float4v Lf0, Lf1;
    #pragma unroll
    for (int e=0;e<4;e++){ Lf0[e]=0.f; Lf1[e]=0.f; }
    #pragma unroll
    for (int ks=0; ks<16; ks++){
      int gch = ks*4 + l4;
      int sA = l15;
      short8 b0 = *(const short8*)(&lK[cur][sA*512 + ((gch ^ (sA&7))*8)]);
      int sB = 16 + l15;
      short8 b1 = *(const short8*)(&lK[cur][sB*512 + ((gch ^ (sB&7))*8)]);
      Lf0 = __builtin_amdgcn_mfma_f32_16x16x32_bf16(qf[ks], b0, Lf0, 0,0,0);
      Lf1 = __builtin_amdgcn_mfma_f32_16x16x32_bf16(qf[ks], b1, Lf1, 0,0,0);
    }

    // ---- in-lane online softmax (row t=l4*4+r; reduce over 16 lanes)
    float v0[4], v1[4], mxA[4];
    bool need = false;
    #pragma unroll
    for (int r=0; r<4; r++){
      v0[r] = Lf0[r]*SCALE_QK; v1[r] = Lf1[r]*SCALE_QK;
      float mx = fmaxf(v0[r], v1[r]);
      mx = fmaxf(mx, __shfl_xor(mx,1));
      mx = fmaxf(mx, __shfl_xor(mx,2));
      mx = fmaxf(mx, __shfl_xor(mx,4));
      mx = fmaxf(mx, __shfl_xor(mx,8));
      mxA[r] = mx;
      need = need || (mx > M_r[r] + 4.0f);
    }
    int nw = __any((int)need);           // wave-uniform
    float al[4];
    #pragma unroll
    for (int r=0; r<4; r++){
      float mnew = nw ? fmaxf(M_r[r], mxA[r]) : M_r[r];
      al[r] = nw ? exp2f((M_r[r] - mnew)*LOG2E_) : 1.0f;
      float p0 = exp2f((v0[r] - mnew)*LOG2E_);
      float p1 = exp2f((v1[r] - mnew)*LOG2E_);
      L_r[r] = L_r[r]*al[r] + (p0 + p1);
      M_r[r] = mnew;
      int tl_ = l4*4 + r;
      lPw[tl_*40 + l15]      = f2b(p0);
      lPw[tl_*40 + 16 + l15] = f2b(p1);
    }

    // ---- PV (same wave's P; ds_write->ds_read ordered by lgkmcnt, no barrier)
    {
      if (nw){
        #pragma unroll
        for (int ct=0; ct<32; ct++)
          #pragma unroll
          for (int r=0; r<4; r++) acc[ct][r] *= al[r];
      }
      short8 paf = *(const short8*)(lPw + l15*40 + l4*8);   // A: P[t=l15][s=l4*8+j]
      const u16* vbase = &lV[cur][l4*4096 + l15*8];
      __builtin_amdgcn_s_setprio(1);
      #pragma unroll
      for (int ct=0; ct<32; ct++){
        short8 vbf = *(const short8*)(vbase + ct*128);      // B: V[s=l4*8+j][c=ct*16+l15]
        acc[ct] = __builtin_amdgcn_mfma_f32_16x16x32_bf16(paf, vbf, acc[ct], 0,0,0);
      }
      __builtin_amdgcn_s_setprio(0);
    }
    __syncthreads();   // buffer swap: next tile's K/V gloads complete + LDS ordered
    cur ^= 1;
  }

  // ---- epilogue: full row-sum (in-reg), divide, write at(b,t,c) bf16
  float iv[4];
  #pragma unroll
  for (int r=0; r<4; r++){
    float s = L_r[r];
    s += __shfl_xor(s,1); s += __shfl_xor(s,2);
    s += __shfl_xor(s,4); s += __shfl_xor(s,8);
    iv[r] = 1.f/s;
  }
  #pragma unroll
  for (int ct=0; ct<32; ct++){
    int cc = ct*16 + l15;
    #pragma unroll
    for (int r=0; r<4; r++){
      int tt = t0 + w*16 + l4*4 + r;
      at[((size_t)b*NT + tt)*NC + cc] = f2b(acc[ct][r]*iv[r]);
    }
  }
}

// ---------------- k6: proj GEMM + bias + residual (f32 out) ----------------
__global__ __launch_bounds__(256,2) void k_proj_res(const u16* __restrict__ wp, const u16* __restrict__ at,
                                                    const float* __restrict__ pb, const float* __restrict__ x,
                                                    float* __restrict__ out){
  __shared__ __align__(16) u16 lA[2][8192];
  __shared__ __align__(16) u16 lB[2][8192];
  int b = blockIdx.z, t0 = blockIdx.x*128, o0 = blockIdx.y*128;
  int tid = threadIdx.x, w = tid>>6, l = tid&63;
  int wm = (w&1)*64, wn = (w>>1)*64;
  float4v acc[4][4];
  #pragma unroll
  for (int i=0;i<4;i++)
    #pragma unroll
    for (int j=0;j<4;j++)
      #pragma unroll
      for (int e=0;e<4;e++) acc[i][j][e] = 0.f;
  const u16* Ab = wp + (size_t)o0*NC;
  const u16* Bb = at + ((size_t)b*NT + t0)*NC;
  stage128(Ab, lA[0], w, l);
  stage128(Bb, lB[0], w, l);
  __syncthreads();
  for (int it=0; it<8; it++){
    int cur = it&1;
    if (it < 7){
      stage128(Ab + (it+1)*64, lA[cur^1], w, l);
      stage128(Bb + (it+1)*64, lB[cur^1], w, l);
    }
    tile_mac(lA[cur], lB[cur], acc, wm, wn, l);
    __syncthreads();
  }
  #pragma unroll
  for (int fm=0; fm<4; fm++)
    #pragma unroll
    for (int r=0; r<4; r++){
      int o = o0 + wm + fm*16 + (l>>4)*4 + r;
      float bs = pb[o];
      #pragma unroll
      for (int fn=0; fn<4; fn++){
        int t = t0 + wn + fn*16 + (l&15);
        size_t idx = ((size_t)b*NC + o)*NT + t;
        out[idx] = acc[fm][fn][r] + bs + x[idx];
      }
    }
}

extern "C" void kernel_launch(void* const* d_in, const int* in_sizes, int n_in,
                              void* d_out, int out_size, void* d_ws, size_t ws_size,
                              hipStream_t stream){
  const float* x    = (const float*)d_in[0];
  const float* gnw  = (const float*)d_in[1];
  const float* gnb  = (const float*)d_in[2];
  const float* qkvw = (const float*)d_in[3];
  const float* qkvb = (const float*)d_in[4];
  const float* pw   = (const float*)d_in[5];
  const float* pb   = (const float*)d_in[6];
  float* out = (float*)d_out;

  char* ws = (char*)d_ws;
  float* stats = (float*)ws;
  u16* h   = (u16*)(ws + 4096);
  u16* qkv = (u16*)(ws + 4096 + 33554432);
  u16* vct = (u16*)(ws + 4096 + 33554432 + 100663296);
  u16* wqb = (u16*)(ws + 4096 + 33554432 + 100663296 + 33554432);
  u16* wpb = (u16*)(ws + 4096 + 33554432 + 100663296 + 33554432 + 1572864);
  u16* at  = h;

  k_cvt<<<3072, 256, 0, stream>>>(qkvw, wqb, 786432);
  k_cvt<<<1024, 256, 0, stream>>>(pw, wpb, 262144);
  k_stats<<<256, 256, 0, stream>>>(x, stats);
  k_gn_apply<<<dim3(64,8,8), 256, 0, stream>>>(x, stats, gnw, gnb, h);
  k_qkv_gemm<<<dim3(12,32,8), 256, 0, stream>>>(h, wqb, qkvb, qkv, vct);
  k_attn<<<256, 512, 0, stream>>>(qkv, vct, at);
  k_proj_res<<<dim3(32,4,8), 256, 0, stream>>>(wpb, at, pb, x, out);
}